// Round 25
// baseline (44.317 us; speedup 1.0000x reference)
//
#include <hip/hip_runtime.h>
#include <math.h>

namespace {
constexpr int RADIUS = 9;
constexpr float EPSV = 1e-5f;
constexpr int N_ = 2, C_ = 64, H_ = 128, W_ = 192;
constexpr int HW  = H_ * W_;            // 24576
constexpr int CHW = C_ * HW;
constexpr size_t OUT1 = (size_t)N_ * 81 * HW;

constexpr int XT = 64, YT = 4;          // spatial tile; i fully in grid.z
constexpr int NT = 256;                 // 4 waves; wave = channel-group of 16
constexpr int NW = 4;
constexpr int ROUNDS = 16;              // 1 channel / wave / round
constexpr int MROWS = 4;
constexpr int NCH = 19;
constexpr int MCOLS = 76;
constexpr int MAP_SLOTS = MROWS * NCH;  // 76
constexpr int OFF_INVM = 5 * 256 * 4;   // 5120 (epilogue reduce overlay first)
constexpr int LDS_F = OFF_INVM + MROWS * MCOLS;   // 5424 floats = 21696 B
constexpr int SW = 32;                  // bf16 strip row width (4 patterns)
}

__device__ __forceinline__ unsigned short f2bf(float f) {   // RTN-even
    unsigned u = __float_as_uint(f);
    unsigned r = ((u >> 16) & 1u) + 0x7fffu;
    return (unsigned short)((u + r) >> 16);
}
__device__ __forceinline__ float bflo(unsigned d) { return __uint_as_float(d << 16); }
__device__ __forceinline__ float bfhi(unsigned d) { return __uint_as_float(d & 0xffff0000u); }

// ---------------------------------------------------------------------------
// Kernel 1: channel L2 norms; emits invM (f32), imgs = bf16(img*invI),
// mapb = bf16(map), and 4 left-edge replicate strip patterns per (n,c,y):
//   S8a@0  = window e[-10..-3] -> {m0 x8}
//   S8b@8  = window e[-6..1]   -> {m0 x7, m1}
//   S8c@16 = window e[-2..5]   -> {m0,m0,m0,m1,m2,m3,m4,m5}
//   S4 @24 = window e[-2..1]   -> {m0,m0,m0,m1}
// ---------------------------------------------------------------------------
__global__ __launch_bounds__(256)
void norms_kernel(const float* __restrict__ img,
                  const float* __restrict__ mp,
                  float* __restrict__ invM,
                  unsigned short* __restrict__ imgs,
                  unsigned short* __restrict__ mapb,
                  unsigned short* __restrict__ stripB) {
    __shared__ float4 sI[8][32], sM[8][32];
    const int tid = threadIdx.x;
    const int cg = tid >> 5;               // 0..7 (8 channels each)
    const int s  = tid & 31;
    const int q4 = blockIdx.x * 32 + s;    // [0, 12288)
    const int n = q4 / (HW / 4);
    const int pix = (q4 - n * (HW / 4)) * 4;
    const int y = pix / W_;
    const int x = pix - y * W_;
    const float* pi = img + (size_t)n * CHW + pix;
    const float* pm = mp  + (size_t)n * CHW + pix;
    const bool e = (x == 0);

    float4 iv[8], mv[8];
    float4 si = {0.f, 0.f, 0.f, 0.f}, sm = {0.f, 0.f, 0.f, 0.f};
#pragma unroll
    for (int cc = 0; cc < 8; ++cc) {
        iv[cc] = *(const float4*)(pi + (size_t)(cg * 8 + cc) * HW);
        mv[cc] = *(const float4*)(pm + (size_t)(cg * 8 + cc) * HW);
        si.x = fmaf(iv[cc].x, iv[cc].x, si.x); si.y = fmaf(iv[cc].y, iv[cc].y, si.y);
        si.z = fmaf(iv[cc].z, iv[cc].z, si.z); si.w = fmaf(iv[cc].w, iv[cc].w, si.w);
        sm.x = fmaf(mv[cc].x, mv[cc].x, sm.x); sm.y = fmaf(mv[cc].y, mv[cc].y, sm.y);
        sm.z = fmaf(mv[cc].z, mv[cc].z, sm.z); sm.w = fmaf(mv[cc].w, mv[cc].w, sm.w);
    }
    sI[cg][s] = si; sM[cg][s] = sm;
    __syncthreads();
    float4 ti = {0.f, 0.f, 0.f, 0.f}, tm = {0.f, 0.f, 0.f, 0.f};
#pragma unroll
    for (int g = 0; g < 8; ++g) {
        float4 a = sI[g][s], b = sM[g][s];
        ti.x += a.x; ti.y += a.y; ti.z += a.z; ti.w += a.w;
        tm.x += b.x; tm.y += b.y; tm.z += b.z; tm.w += b.w;
    }
    float4 vi;
    vi.x = 1.f / (sqrtf(ti.x) + EPSV); vi.y = 1.f / (sqrtf(ti.y) + EPSV);
    vi.z = 1.f / (sqrtf(ti.z) + EPSV); vi.w = 1.f / (sqrtf(ti.w) + EPSV);
    if (cg == 0) {
        float4 vm;
        vm.x = 1.f / (sqrtf(tm.x) + EPSV); vm.y = 1.f / (sqrtf(tm.y) + EPSV);
        vm.z = 1.f / (sqrtf(tm.z) + EPSV); vm.w = 1.f / (sqrtf(tm.w) + EPSV);
        *(float4*)(invM + (size_t)n * HW + pix) = vm;
    }
    unsigned short* ib = imgs + (size_t)n * CHW + pix;
    unsigned short* mb = mapb + (size_t)n * CHW + pix;
#pragma unroll
    for (int cc = 0; cc < 8; ++cc) {
        const size_t o = (size_t)(cg * 8 + cc) * HW;
        ushort4 a4;
        a4.x = f2bf(iv[cc].x * vi.x); a4.y = f2bf(iv[cc].y * vi.y);
        a4.z = f2bf(iv[cc].z * vi.z); a4.w = f2bf(iv[cc].w * vi.w);
        *(ushort4*)(ib + o) = a4;
        ushort4 b4;
        b4.x = f2bf(mv[cc].x); b4.y = f2bf(mv[cc].y);
        b4.z = f2bf(mv[cc].z); b4.w = f2bf(mv[cc].w);
        *(ushort4*)(mb + o) = b4;
        if (e) {
            const float* mrow = pm + o;    // = map row start (x==0)
            unsigned short b0 = b4.x, b1 = b4.y;
            unsigned short bb2 = b4.z, bb3 = b4.w;
            unsigned short bb4 = f2bf(mrow[4]), bb5 = f2bf(mrow[5]);
            unsigned short* sr = stripB + ((size_t)(n * C_ + cg * 8 + cc) * H_ + y) * SW;
            ushort4 q0 = {b0, b0, b0, b0};
            ushort4 q1 = {b0, b0, b0, b1};
            ushort4 q2 = {bb2, bb3, bb4, bb5};
            *(ushort4*)(sr + 0)  = q0; *(ushort4*)(sr + 4)  = q0;   // S8a
            *(ushort4*)(sr + 8)  = q0; *(ushort4*)(sr + 12) = q1;   // S8b
            *(ushort4*)(sr + 16) = q1; *(ushort4*)(sr + 20) = q2;   // S8c
            *(ushort4*)(sr + 24) = q1;                              // S4
        }
    }
}

// ---------------------------------------------------------------------------
// Kernel 2: raw correlation on bf16 operands. No LDS/barriers in main loop.
// Per round: 16B+8B+4B map window + 8B img = 36 B/lane; unpack via shift/mask;
// 36 FMAs. Left edge = pointer redirect into strip patterns:
//   e0 = 4xc-10 (x0==0): -10 -> S8a, -6 -> S8b, -2 -> S8c ; eB=-2 -> S4.
//   out_diss = sum_c mapb * imgs   (invI pre-folded into imgs)
//   out_cos  = 1 - invM[p'] * out_diss
// ---------------------------------------------------------------------------
__global__ __launch_bounds__(NT)
void corr_kernel(const unsigned short* __restrict__ imgs,
                 const unsigned short* __restrict__ mapb,
                 const float* __restrict__ invMg,
                 const unsigned short* __restrict__ stripB,
                 float* __restrict__ out) {
    __shared__ float smem[LDS_F];

    const int bz = blockIdx.z;             // n*9 + i
    const int n    = bz / RADIUS;
    const int iOff = bz - n * RADIUS;
    const int x0 = blockIdx.x * XT;
    const int y0 = blockIdx.y * YT;
    const int tid = threadIdx.x;
    const int w    = tid >> 6;             // wave = channel group (16 ch)
    const int lane = tid & 63;
    const int ty = lane >> 4;              // 0..3
    const int xc = lane & 15;              // 0..15
    const int ch0 = w * 16;

    // ---- invM halo (76 float4; epilogue-only, synced by epilogue barrier) ----
    if (tid < MAP_SLOTS) {
        int r = tid / NCH, k = tid - r * NCH;
        int gy = min(max(y0 + iOff - RADIUS + r, 0), H_ - 1);
        int gxs = x0 - 12 + 4 * k;
        const float* src = invMg + n * HW + (size_t)gy * W_;
        float4 v;
        if (gxs >= 0) v = *(const float4*)(src + gxs);
        else { float s0 = src[0]; v.x = s0; v.y = s0; v.z = s0; v.w = s0; }
        *(float4*)&smem[OFF_INVM + r * MCOLS + 4 * k] = v;
    }

    // ---- per-lane descriptors: window elems [4xc-9, 4xc+2] via 8+4+2 chunks ----
    const int gy = min(max(y0 + ty + iOff - RADIUS, 0), H_ - 1);
    const unsigned short* rowb = mapb + (size_t)n * CHW + (size_t)ch0 * HW
                               + (size_t)gy * W_;                    // batch offset!
    const unsigned short* srow = stripB + ((size_t)(n * C_ + ch0) * H_ + gy) * SW;
    const unsigned short *pA, *pB2, *pC;
    int sA, sB, sC;
    {
        const int e0 = x0 + 4 * xc - 10;       // chunk A start (8 elems)
        if (e0 <= -8)      { pA = srow + 0;  sA = H_ * SW; }   // e0=-10 -> S8a
        else if (e0 <= -4) { pA = srow + 8;  sA = H_ * SW; }   // e0=-6  -> S8b
        else if (e0 < 0)   { pA = srow + 16; sA = H_ * SW; }   // e0=-2  -> S8c
        else               { pA = rowb + e0; sA = HW; }
        const int eB = e0 + 8;                 // chunk B start (4 elems)
        if (eB < 0)        { pB2 = srow + 24; sB = H_ * SW; }  // eB=-2  -> S4
        else               { pB2 = rowb + eB; sB = HW; }
        pC = rowb + e0 + 12; sC = HW;          // chunk C (2 elems) never OOB
    }
    const unsigned short* pI2 = imgs + (size_t)n * CHW + (size_t)ch0 * HW
                              + (size_t)(y0 + ty) * W_ + x0 + 4 * xc;  // batch offset!

    float acc[4][RADIUS];
#pragma unroll
    for (int p = 0; p < 4; ++p)
#pragma unroll
        for (int j = 0; j < RADIUS; ++j) acc[p][j] = 0.f;

    // ---- main loop: pure register dataflow, no LDS, no barriers ----
#pragma unroll 4
    for (int ri = 0; ri < ROUNDS; ++ri) {
        unsigned dA[4]; __builtin_memcpy(dA, pA  + (size_t)ri * sA, 16);
        unsigned dB[2]; __builtin_memcpy(dB, pB2 + (size_t)ri * sB, 8);
        unsigned dC;    __builtin_memcpy(&dC, pC + (size_t)ri * sC, 4);
        unsigned dI[2]; __builtin_memcpy(dI, pI2 + (size_t)ri * HW, 8);
        // window wv[k] = elem(4xc-9+k), k=0..11 (chunk elem 0 = 4xc-10 unused)
        float wv[12];
        wv[0]  = bfhi(dA[0]); wv[1]  = bflo(dA[1]); wv[2]  = bfhi(dA[1]);
        wv[3]  = bflo(dA[2]); wv[4]  = bfhi(dA[2]); wv[5]  = bflo(dA[3]);
        wv[6]  = bfhi(dA[3]); wv[7]  = bflo(dB[0]); wv[8]  = bfhi(dB[0]);
        wv[9]  = bflo(dB[1]); wv[10] = bfhi(dB[1]); wv[11] = bflo(dC);
        const float a[4] = {bflo(dI[0]), bfhi(dI[0]), bflo(dI[1]), bfhi(dI[1])};
#pragma unroll
        for (int p = 0; p < 4; ++p)
#pragma unroll
            for (int j = 0; j < RADIUS; ++j)
                acc[p][j] = fmaf(wv[p + j], a[p], acc[p][j]);
    }

    // ==== epilogue: 4-way cross-wave reduce, SoA float4 layout ====
    __syncthreads();                       // invM halo ready; LDS free
    const int slot = tid;                  // 0..255
    const int y  = y0 + ty;
    const int xb = x0 + 4 * xc;
    const float* wmRow = &smem[OFF_INVM + ty * MCOLS + 4 * xc + 3];
    float* ocB = out + (size_t)(n * 81 + iOff * RADIUS) * HW + (size_t)y * W_ + xb;

    // ---- pass 1: planes q0..q3 ----
#pragma unroll
    for (int q = 0; q < 4; ++q) {
        float4 v = {acc[0][q], acc[1][q], acc[2][q], acc[3][q]};
        *(float4*)&smem[(q * 256 + slot) * 4] = v;
    }
    __syncthreads();
    {   // waves 0..3 store j = w
        const int j = w;
        float4 s = {0.f, 0.f, 0.f, 0.f};
#pragma unroll
        for (int g = 0; g < NW; ++g) {
            float4 v = *(const float4*)&smem[(j * 256 + g * 64 + lane) * 4];
            s.x += v.x; s.y += v.y; s.z += v.z; s.w += v.w;
        }
        float4 vc;
        vc.x = 1.f - s.x * wmRow[j + 0];
        vc.y = 1.f - s.y * wmRow[j + 1];
        vc.z = 1.f - s.z * wmRow[j + 2];
        vc.w = 1.f - s.w * wmRow[j + 3];
        *(float4*)(ocB + (size_t)j * HW) = vc;
        *(float4*)(ocB + OUT1 + (size_t)j * HW) = s;
    }
    __syncthreads();
    // ---- pass 2: planes q4..q8 ----
#pragma unroll
    for (int q = 0; q < 5; ++q) {
        float4 v = {acc[0][q + 4], acc[1][q + 4], acc[2][q + 4], acc[3][q + 4]};
        *(float4*)&smem[(q * 256 + slot) * 4] = v;
    }
    __syncthreads();
    {   // waves 0..3 store j = 4 + w
        const int j = 4 + w;
        float4 s = {0.f, 0.f, 0.f, 0.f};
#pragma unroll
        for (int g = 0; g < NW; ++g) {
            float4 v = *(const float4*)&smem[((j - 4) * 256 + g * 64 + lane) * 4];
            s.x += v.x; s.y += v.y; s.z += v.z; s.w += v.w;
        }
        float4 vc;
        vc.x = 1.f - s.x * wmRow[j + 0];
        vc.y = 1.f - s.y * wmRow[j + 1];
        vc.z = 1.f - s.z * wmRow[j + 2];
        vc.w = 1.f - s.w * wmRow[j + 3];
        *(float4*)(ocB + (size_t)j * HW) = vc;
        *(float4*)(ocB + OUT1 + (size_t)j * HW) = s;
    }
    if (w == 0) {                          // wave 0 also stores j = 8
        const int j = 8;
        float4 s = {0.f, 0.f, 0.f, 0.f};
#pragma unroll
        for (int g = 0; g < NW; ++g) {
            float4 v = *(const float4*)&smem[(4 * 256 + g * 64 + lane) * 4];
            s.x += v.x; s.y += v.y; s.z += v.z; s.w += v.w;
        }
        float4 vc;
        vc.x = 1.f - s.x * wmRow[j + 0];
        vc.y = 1.f - s.y * wmRow[j + 1];
        vc.z = 1.f - s.z * wmRow[j + 2];
        vc.w = 1.f - s.w * wmRow[j + 3];
        *(float4*)(ocB + (size_t)j * HW) = vc;
        *(float4*)(ocB + OUT1 + (size_t)j * HW) = s;
    }
}

extern "C" void kernel_launch(void* const* d_in, const int* in_sizes, int n_in,
                              void* d_out, int out_size, void* d_ws, size_t ws_size,
                              hipStream_t stream) {
    const float* img = (const float*)d_in[0];
    const float* mp  = (const float*)d_in[1];
    float* out = (float*)d_out;
    // ws layout (all 64B-aligned): invM f32 | strips bf16 | imgs bf16 | mapb bf16
    float* invM = (float*)d_ws;                                   // 196608 B
    unsigned short* stripB = (unsigned short*)((char*)d_ws + 196608);   // 1 MiB
    unsigned short* imgs   = (unsigned short*)((char*)d_ws + 196608 + 1048576);
    unsigned short* mapb   = imgs + (size_t)N_ * CHW;             // +6.29 MB each

    norms_kernel<<<(N_ * HW / 4) / 32, 256, 0, stream>>>(img, mp, invM,
                                                         imgs, mapb, stripB);

    dim3 grid(W_ / XT, H_ / YT, N_ * RADIUS);     // 3 x 32 x 18 = 1728 blocks
    corr_kernel<<<grid, NT, 0, stream>>>(imgs, mapb, invM, stripB, out);
}

// Round 26
// 33.238 us; speedup vs baseline: 1.3333x; 1.3333x over previous
//
#include <hip/hip_runtime.h>
#include <math.h>

namespace {
constexpr int RADIUS = 9;
constexpr float EPSV = 1e-5f;
constexpr int N_ = 2, C_ = 64, H_ = 128, W_ = 192;
constexpr int HW  = H_ * W_;            // 24576
constexpr int CHW = C_ * HW;
constexpr size_t OUT1 = (size_t)N_ * 81 * HW;

constexpr int XT = 64, YT = 4;          // spatial tile; i fully in grid.z
constexpr int NT = 256;                 // 4 waves; wave = channel-group of 16
constexpr int NW = 4;
constexpr int ROUNDS = 16;              // 1 channel / wave / round
constexpr int MROWS = 4;
constexpr int NCH = 19;
constexpr int MCOLS = 76;
constexpr int MAP_SLOTS = MROWS * NCH;  // 76
constexpr int OFF_INVM = 5 * 256 * 4;   // 5120 (epilogue reduce overlay first)
constexpr int LDS_F = OFF_INVM + MROWS * MCOLS;   // 5424 floats = 21696 B
}

// ---------------------------------------------------------------------------
// Kernel 1: invM (map channel-norms) + left-edge strips.
//   strip [(n*C+c)*H + y][0..3] = {m0,m0,m0,m0}   (m_k = map[n,c,y,k])
//   strip2[(n*C+c)*H + y][0..3] = {m0,m0,m1,m2}   (window starting at x=-1)
// 256 threads = 8 c-groups x 32 q4-pixels; 384 blocks.
// ---------------------------------------------------------------------------
__global__ __launch_bounds__(256)
void norms_kernel(const float* __restrict__ mp,
                  float* __restrict__ invM,
                  float* __restrict__ strip,
                  float* __restrict__ strip2) {
    __shared__ float4 sM[8][32];
    const int tid = threadIdx.x;
    const int cg = tid >> 5;               // 0..7 (8 channels each)
    const int s  = tid & 31;
    const int q4 = blockIdx.x * 32 + s;    // [0, 12288)
    const int n = q4 / (HW / 4);
    const int pix = (q4 - n * (HW / 4)) * 4;
    const int y = pix / W_;
    const int x = pix - y * W_;
    const float* pm = mp + (size_t)n * CHW + pix;
    const bool e = (x == 0);
    float* sp  = strip  + ((size_t)(n * C_ + cg * 8) * H_ + y) * 4;
    float* sp2 = strip2 + ((size_t)(n * C_ + cg * 8) * H_ + y) * 4;

    float4 sm = {0.f, 0.f, 0.f, 0.f};
#pragma unroll
    for (int cc = 0; cc < 8; ++cc) {
        float4 b = *(const float4*)(pm + (size_t)(cc + 0) * HW + (size_t)cg * 8 * HW);
        sm.x = fmaf(b.x, b.x, sm.x); sm.y = fmaf(b.y, b.y, sm.y);
        sm.z = fmaf(b.z, b.z, sm.z); sm.w = fmaf(b.w, b.w, sm.w);
        if (e) {
            float4 v1 = {b.x, b.x, b.x, b.x};
            float4 v2 = {b.x, b.x, b.y, b.z};
            *(float4*)(sp  + (size_t)cc * H_ * 4) = v1;
            *(float4*)(sp2 + (size_t)cc * H_ * 4) = v2;
        }
    }
    sM[cg][s] = sm;
    __syncthreads();
    if (tid < 32) {
        float4 b = sM[0][tid];
#pragma unroll
        for (int g = 1; g < 8; ++g) {
            float4 v = sM[g][tid];
            b.x += v.x; b.y += v.y; b.z += v.z; b.w += v.w;
        }
        int q4b = blockIdx.x * 32 + tid;
        int nb = q4b / (HW / 4);
        int pixb = (q4b - nb * (HW / 4)) * 4;
        float4 vm;
        vm.x = 1.f / (sqrtf(b.x) + EPSV); vm.y = 1.f / (sqrtf(b.y) + EPSV);
        vm.z = 1.f / (sqrtf(b.z) + EPSV); vm.w = 1.f / (sqrtf(b.w) + EPSV);
        *(float4*)(invM + (size_t)nb * HW + pixb) = vm;
    }
}

// ---------------------------------------------------------------------------
// Kernel 2: raw correlation + inline img-norm. No LDS/barriers in main loop.
// Per round: 3 dword-aligned 16B map loads (exact 12-float window) + 1 img
// float4; 40 FMAs. Left edge = pointer redirect to strip/strip2.
//   dotRaw[p,(i,j)] = sum_c map[c, clamp(p+(i,j)-9)] * img[c, p]
//   out_diss = invI[p]*dotRaw ;  out_cos = 1 - invM[p']*out_diss
// ---------------------------------------------------------------------------
__global__ __launch_bounds__(NT)
void corr_kernel(const float* __restrict__ img,
                 const float* __restrict__ mp,
                 const float* __restrict__ invMg,
                 const float* __restrict__ strip,
                 const float* __restrict__ strip2,
                 float* __restrict__ out) {
    __shared__ float smem[LDS_F];

    const int bz = blockIdx.z;             // n*9 + i
    const int n    = bz / RADIUS;
    const int iOff = bz - n * RADIUS;
    const int x0 = blockIdx.x * XT;
    const int y0 = blockIdx.y * YT;
    const int tid = threadIdx.x;
    const int w    = tid >> 6;             // wave = channel group (16 ch)
    const int lane = tid & 63;
    const int ty = lane >> 4;              // 0..3
    const int xc = lane & 15;              // 0..15
    const int ch0 = w * 16;

    const float* imgN = img + (size_t)n * CHW;
    const float* mapN = mp  + (size_t)n * CHW;

    // ---- invM halo (76 float4; epilogue-only, synced by epilogue barrier) ----
    if (tid < MAP_SLOTS) {
        int r = tid / NCH, k = tid - r * NCH;
        int gy = min(max(y0 + iOff - RADIUS + r, 0), H_ - 1);
        int gxs = x0 - 12 + 4 * k;
        const float* src = invMg + n * HW + (size_t)gy * W_;
        float4 v;
        if (gxs >= 0) v = *(const float4*)(src + gxs);
        else { float s0 = src[0]; v.x = s0; v.y = s0; v.z = s0; v.w = s0; }
        *(float4*)&smem[OFF_INVM + r * MCOLS + 4 * k] = v;
    }

    // ---- per-lane direct-read descriptors (3 chunks, window = x0+4xc-9+[0,12)) ----
    const int gy = min(max(y0 + ty + iOff - RADIUS, 0), H_ - 1);
    const float* rowp = mapN + (size_t)ch0 * HW + (size_t)gy * W_;
    const float* stripRow  = strip  + ((size_t)(n * C_ + ch0) * H_ + gy) * 4;
    const float* stripRow2 = strip2 + ((size_t)(n * C_ + ch0) * H_ + gy) * 4;
    const float *pd0, *pd1, *pd2;
    int sd0, sd1, sd2;
    {
        const int gxb = x0 + 4 * xc - 9;
        if (gxb <= -4)     { pd0 = stripRow;  sd0 = H_ * 4; }
        else if (gxb < 0)  { pd0 = stripRow2; sd0 = H_ * 4; }   // gxb == -1
        else               { pd0 = rowp + gxb; sd0 = HW; }
        const int g1 = gxb + 4;
        if (g1 <= -4)      { pd1 = stripRow;  sd1 = H_ * 4; }
        else if (g1 < 0)   { pd1 = stripRow2; sd1 = H_ * 4; }
        else               { pd1 = rowp + g1;  sd1 = HW; }
        const int g2 = gxb + 8;
        if (g2 < 0)        { pd2 = stripRow2; sd2 = H_ * 4; }   // g2 == -1 only
        else               { pd2 = rowp + g2;  sd2 = HW; }
    }
    const float* pI = imgN + (size_t)ch0 * HW + (size_t)(y0 + ty) * W_ + x0 + 4 * xc;

    float acc[4][RADIUS];
#pragma unroll
    for (int p = 0; p < 4; ++p)
#pragma unroll
        for (int j = 0; j < RADIUS; ++j) acc[p][j] = 0.f;
    float si[4] = {0.f, 0.f, 0.f, 0.f};

    // ---- main loop: pure register dataflow, no LDS, no barriers ----
#pragma unroll 4
    for (int ri = 0; ri < ROUNDS; ++ri) {
        float wreg[12];
        __builtin_memcpy(&wreg[0], pd0 + (size_t)ri * sd0, 16);
        __builtin_memcpy(&wreg[4], pd1 + (size_t)ri * sd1, 16);
        __builtin_memcpy(&wreg[8], pd2 + (size_t)ri * sd2, 16);
        const float4 a4 = *(const float4*)(pI + (size_t)ri * HW);
        const float a[4] = {a4.x, a4.y, a4.z, a4.w};
        si[0] = fmaf(a[0], a[0], si[0]);
        si[1] = fmaf(a[1], a[1], si[1]);
        si[2] = fmaf(a[2], a[2], si[2]);
        si[3] = fmaf(a[3], a[3], si[3]);
#pragma unroll
        for (int p = 0; p < 4; ++p)
#pragma unroll
            for (int j = 0; j < RADIUS; ++j)
                acc[p][j] = fmaf(wreg[p + j], a[p], acc[p][j]);
    }

    // ==== epilogue: 4-way cross-wave reduce, SoA float4 layout ====
    __syncthreads();                       // invM halo ready; LDS free
    const int slot = tid;                  // 0..255
#pragma unroll
    for (int q = 0; q < 4; ++q) {
        float4 v = {acc[0][q], acc[1][q], acc[2][q], acc[3][q]};
        *(float4*)&smem[(q * 256 + slot) * 4] = v;
    }
    { float4 v = {si[0], si[1], si[2], si[3]}; *(float4*)&smem[(4 * 256 + slot) * 4] = v; }
    __syncthreads();
    float4 sv = {0.f, 0.f, 0.f, 0.f};
#pragma unroll
    for (int g = 0; g < NW; ++g) {
        float4 v = *(const float4*)&smem[(4 * 256 + g * 64 + lane) * 4];
        sv.x += v.x; sv.y += v.y; sv.z += v.z; sv.w += v.w;
    }
    float4 vI;
    vI.x = 1.f / (sqrtf(sv.x) + EPSV);
    vI.y = 1.f / (sqrtf(sv.y) + EPSV);
    vI.z = 1.f / (sqrtf(sv.z) + EPSV);
    vI.w = 1.f / (sqrtf(sv.w) + EPSV);

    const int y  = y0 + ty;
    const int xb = x0 + 4 * xc;
    const float* wmRow = &smem[OFF_INVM + ty * MCOLS + 4 * xc + 3];
    float* ocB = out + (size_t)(n * 81 + iOff * RADIUS) * HW + (size_t)y * W_ + xb;

    {   // waves 0..3 store j = w
        const int j = w;
        float4 s = {0.f, 0.f, 0.f, 0.f};
#pragma unroll
        for (int g = 0; g < NW; ++g) {
            float4 v = *(const float4*)&smem[(j * 256 + g * 64 + lane) * 4];
            s.x += v.x; s.y += v.y; s.z += v.z; s.w += v.w;
        }
        float4 vd, vc;
        vd.x = s.x * vI.x; vd.y = s.y * vI.y; vd.z = s.z * vI.z; vd.w = s.w * vI.w;
        vc.x = 1.f - vd.x * wmRow[j + 0];
        vc.y = 1.f - vd.y * wmRow[j + 1];
        vc.z = 1.f - vd.z * wmRow[j + 2];
        vc.w = 1.f - vd.w * wmRow[j + 3];
        *(float4*)(ocB + (size_t)j * HW) = vc;
        *(float4*)(ocB + OUT1 + (size_t)j * HW) = vd;
    }
    __syncthreads();
#pragma unroll
    for (int q = 0; q < 5; ++q) {
        float4 v = {acc[0][q + 4], acc[1][q + 4], acc[2][q + 4], acc[3][q + 4]};
        *(float4*)&smem[(q * 256 + slot) * 4] = v;
    }
    __syncthreads();
    {   // waves 0..3 store j = 4 + w
        const int j = 4 + w;
        float4 s = {0.f, 0.f, 0.f, 0.f};
#pragma unroll
        for (int g = 0; g < NW; ++g) {
            float4 v = *(const float4*)&smem[((j - 4) * 256 + g * 64 + lane) * 4];
            s.x += v.x; s.y += v.y; s.z += v.z; s.w += v.w;
        }
        float4 vd, vc;
        vd.x = s.x * vI.x; vd.y = s.y * vI.y; vd.z = s.z * vI.z; vd.w = s.w * vI.w;
        vc.x = 1.f - vd.x * wmRow[j + 0];
        vc.y = 1.f - vd.y * wmRow[j + 1];
        vc.z = 1.f - vd.z * wmRow[j + 2];
        vc.w = 1.f - vd.w * wmRow[j + 3];
        *(float4*)(ocB + (size_t)j * HW) = vc;
        *(float4*)(ocB + OUT1 + (size_t)j * HW) = vd;
    }
    if (w == 0) {                          // wave 0 also stores j = 8
        const int j = 8;
        float4 s = {0.f, 0.f, 0.f, 0.f};
#pragma unroll
        for (int g = 0; g < NW; ++g) {
            float4 v = *(const float4*)&smem[(4 * 256 + g * 64 + lane) * 4];
            s.x += v.x; s.y += v.y; s.z += v.z; s.w += v.w;
        }
        float4 vd, vc;
        vd.x = s.x * vI.x; vd.y = s.y * vI.y; vd.z = s.z * vI.z; vd.w = s.w * vI.w;
        vc.x = 1.f - vd.x * wmRow[j + 0];
        vc.y = 1.f - vd.y * wmRow[j + 1];
        vc.z = 1.f - vd.z * wmRow[j + 2];
        vc.w = 1.f - vd.w * wmRow[j + 3];
        *(float4*)(ocB + (size_t)j * HW) = vc;
        *(float4*)(ocB + OUT1 + (size_t)j * HW) = vd;
    }
}

extern "C" void kernel_launch(void* const* d_in, const int* in_sizes, int n_in,
                              void* d_out, int out_size, void* d_ws, size_t ws_size,
                              hipStream_t stream) {
    const float* img = (const float*)d_in[0];
    const float* mp  = (const float*)d_in[1];
    float* out    = (float*)d_out;
    float* invM   = (float*)d_ws;                 // N_*HW floats
    float* strip  = invM  + N_ * HW;              // N_*C_*H_*4 floats
    float* strip2 = strip + (size_t)N_ * C_ * H_ * 4;

    norms_kernel<<<(N_ * HW / 4) / 32, 256, 0, stream>>>(mp, invM, strip, strip2);

    dim3 grid(W_ / XT, H_ / YT, N_ * RADIUS);     // 3 x 32 x 18 = 1728 blocks
    corr_kernel<<<grid, NT, 0, stream>>>(img, mp, invM, strip, strip2, out);
}